// Round 16
// baseline (626.713 us; speedup 1.0000x reference)
//
#include <hip/hip_runtime.h>

// Problem constants
#define NB 128
#define NL 1024
#define NE 512
#define NA 512
#define ND 512

typedef __attribute__((ext_vector_type(8))) short short8;
typedef __attribute__((ext_vector_type(4))) float f32x4;

static __device__ __forceinline__ unsigned short f2bf(float f) {
  unsigned int u = __float_as_uint(f);
  u += 0x7FFF + ((u >> 16) & 1);   // round-to-nearest-even
  return (unsigned short)(u >> 16);
}

// ---------------------------------------------------------------------------
// Kernel 1: blocks 0..63 pack W_enc -> bf16 MFMA B-fragment order;
// blocks 64..191: att2[b][a] = dec[b]@W_dec[:,a] + b_dec[a] + b_enc[a].
// Bpack: [ki=0..15][nf=0..31][lane=0..63][j=0..7]
__global__ void k_prep(const float* __restrict__ W_enc,
                       unsigned short* __restrict__ Bpack,
                       const float* __restrict__ dec,
                       const float* __restrict__ Wdec,
                       const float* __restrict__ b_enc,
                       const float* __restrict__ b_dec,
                       float* __restrict__ att2) {
  int blk = blockIdx.x;
  int tid = threadIdx.x;  // 512
  if (blk < 64) {
    int t = blk * 512 + tid;
    int lane = t & 63;
    int rest = t >> 6;
    int nf = rest & 31;
    int ki = rest >> 5;
    int col = nf * 16 + (lane & 15);
    int kbase = ki * 32 + (lane >> 4) * 8;
    short8 v;
#pragma unroll
    for (int j = 0; j < 8; ++j)
      v[j] = (short)f2bf(W_enc[(kbase + j) * NA + col]);
    *reinterpret_cast<short8*>(Bpack + (long)t * 8) = v;
  } else {
    int b = blk - 64;
    int a = tid;
    float acc = b_enc[a] + b_dec[a];
    const float* drow = dec + b * ND;
#pragma unroll 8
    for (int d = 0; d < ND; ++d)
      acc += drow[d] * Wdec[d * NA + a];
    att2[b * NA + a] = acc;
  }
}

// ---------------------------------------------------------------------------
// Kernel 2: persistent R10: 512 blocks (2/CU) x 512 thr, each block owns 4
// consecutive 64-row tiles. Per tile, exactly R10's proven schedule (q0,q1
// resident; q2,q3 staged during ki0-7; barrier; ki8-15; epilogue).
// Tile-boundary async-STAGE split (T14): next tile's q0,q1 loads ISSUE right
// after ki15 (fly under scores/softmax/PV), LDS WRITE after B3.
// CRITICAL FIX vs R15: waves_per_eu(4,4) — BOTH bounds pinned. R15's
// single-arg (4) let the compiler target 8 waves/EU -> 64-VGPR cap -> 554 MB
// of scratch spill. (Same failure as R12/R13; R14 proved (4,4) holds 128.)
__global__ __attribute__((amdgpu_waves_per_eu(4, 4))) __launch_bounds__(512)
void k_main(const float* __restrict__ enc,
            const unsigned short* __restrict__ Bpack,
            const float* __restrict__ att2g, const float* __restrict__ wfull,
            float* __restrict__ attg, float* __restrict__ ogp,
            float* __restrict__ mzg) {
  extern __shared__ char smem[];       // 64KB A | 2KB red | 256B p
  const int t = threadIdx.x;
  const int lane = t & 63;
  const int wave = t >> 6;
  const int l15 = lane & 15;
  const int lq = lane >> 4;
  const int blk = blockIdx.x;          // 0..511
  const int batch = blk >> 2;          // 4 blocks per batch
  const int srow16 = t >> 4;           // 0..31 (staging row within half)
  const int scol8 = t & 15;            // staging col8
  long row0 = (long)blk * 256;

  // Staging chunk (Q, FI): row = FI*32 + srow16, k0 = Q*128 + scol8*8.
#define G_LOAD(Q, FI, GA, GB)                                                 \
  {                                                                           \
    int row = (FI)*32 + srow16;                                               \
    const float* src = enc + (row0 + row) * NE + (Q)*128 + scol8 * 8;         \
    GA = *reinterpret_cast<const float4*>(src);                               \
    GB = *reinterpret_cast<const float4*>(src + 4);                           \
  }
#define G_LOADN(Q, FI, GA, GB)                                                \
  {                                                                           \
    int row = (FI)*32 + srow16;                                               \
    const float* src = enc + (row0 + 64 + row) * NE + (Q)*128 + scol8 * 8;    \
    GA = *reinterpret_cast<const float4*>(src);                               \
    GB = *reinterpret_cast<const float4*>(src + 4);                           \
  }
#define G_WRITE(Q, FI, GA, GB)                                                \
  {                                                                           \
    int row = (FI)*32 + srow16;                                               \
    short8 o;                                                                 \
    o[0] = (short)f2bf(GA.x); o[1] = (short)f2bf(GA.y);                       \
    o[2] = (short)f2bf(GA.z); o[3] = (short)f2bf(GA.w);                       \
    o[4] = (short)f2bf(GB.x); o[5] = (short)f2bf(GB.y);                       \
    o[6] = (short)f2bf(GB.z); o[7] = (short)f2bf(GB.w);                       \
    int byt = (row * 1024 + (Q)*256 + scol8 * 16) ^ ((row & 7) << 4);         \
    *reinterpret_cast<short8*>(smem + byt) = o;                               \
  }

  // hoisted epilogue constants (batch fixed per block)
  float a2r[4], wfr[4];
#pragma unroll
  for (int cf = 0; cf < 4; ++cf) {
    int col = wave * 64 + cf * 16 + l15;
    a2r[cf] = att2g[batch * NA + col];
    wfr[cf] = wfull[col];
  }

  // ---- prologue: stage tile 0's quarters 0,1 ----
  {
    float4 h0, h1, h2, h3, h4, h5, h6, h7;
    G_LOAD(0, 0, h0, h1)
    G_LOAD(0, 1, h2, h3)
    G_LOAD(1, 0, h4, h5)
    G_LOAD(1, 1, h6, h7)
    G_WRITE(0, 0, h0, h1)
    G_WRITE(0, 1, h2, h3)
    G_WRITE(1, 0, h4, h5)
    G_WRITE(1, 1, h6, h7)
  }
  __syncthreads();

  const short8* bp = reinterpret_cast<const short8*>(Bpack);
#define K_STEP(KI)                                                            \
  {                                                                           \
    short8 bv0 = bp[((KI)*32 + wave * 4 + 0) * 64 + lane];                    \
    short8 bv1 = bp[((KI)*32 + wave * 4 + 1) * 64 + lane];                    \
    short8 bv2 = bp[((KI)*32 + wave * 4 + 2) * 64 + lane];                    \
    short8 bv3 = bp[((KI)*32 + wave * 4 + 3) * 64 + lane];                    \
    _Pragma("unroll") for (int rt = 0; rt < 4; ++rt) {                        \
      int row = rt * 16 + l15;                                                \
      int byt = (row * 1024 + (KI)*64 + lq * 16) ^ ((row & 7) << 4);          \
      short8 av = *reinterpret_cast<const short8*>(smem + byt);               \
      acc[rt][0] = __builtin_amdgcn_mfma_f32_16x16x32_bf16(av, bv0, acc[rt][0], 0, 0, 0); \
      acc[rt][1] = __builtin_amdgcn_mfma_f32_16x16x32_bf16(av, bv1, acc[rt][1], 0, 0, 0); \
      acc[rt][2] = __builtin_amdgcn_mfma_f32_16x16x32_bf16(av, bv2, acc[rt][2], 0, 0, 0); \
      acc[rt][3] = __builtin_amdgcn_mfma_f32_16x16x32_bf16(av, bv3, acc[rt][3], 0, 0, 0); \
    }                                                                         \
  }

  float* red = (float*)(smem + 65536);        // 512 f
  float* pl = (float*)(smem + 65536 + 2048);  // 64 f

#pragma unroll 1
  for (int T = 0; T < 4; ++T, row0 += 64) {
    const long tg = (long)blk * 4 + T;

    f32x4 acc[4][4];
#pragma unroll
    for (int rt = 0; rt < 4; ++rt)
#pragma unroll
      for (int cf = 0; cf < 4; ++cf) acc[rt][cf] = (f32x4){0.f, 0.f, 0.f, 0.f};

    // ---- ki0-7 with q2,q3 staging (R10 pattern) ----
    {
      float4 g0, g1, g2, g3;
      G_LOAD(2, 0, g0, g1) K_STEP(0)
      G_LOAD(2, 1, g2, g3) K_STEP(1)
      G_WRITE(2, 0, g0, g1) K_STEP(2)
      G_WRITE(2, 1, g2, g3) K_STEP(3)
      G_LOAD(3, 0, g0, g1) K_STEP(4)
      G_LOAD(3, 1, g2, g3) K_STEP(5)
      G_WRITE(3, 0, g0, g1) K_STEP(6)
      G_WRITE(3, 1, g2, g3) K_STEP(7)
    }
    __syncthreads();   // quarters 2,3 staged before ki8 reads
    K_STEP(8)  K_STEP(9)  K_STEP(10) K_STEP(11)
    K_STEP(12) K_STEP(13) K_STEP(14) K_STEP(15)

    // ---- T14 async-STAGE: issue next tile's q0,q1 loads NOW ----
    float4 h0, h1, h2, h3, h4, h5, h6, h7;
    if (T < 3) {
      G_LOADN(0, 0, h0, h1)
      G_LOADN(0, 1, h2, h3)
      G_LOADN(1, 0, h4, h5)
      G_LOADN(1, 1, h6, h7)
    }

    // ---- epilogue (identical math to R10) ----
    float px[4][4];
#pragma unroll
    for (int rt = 0; rt < 4; ++rt)
#pragma unroll
      for (int r = 0; r < 4; ++r) px[rt][r] = 0.f;
#pragma unroll
    for (int cf = 0; cf < 4; ++cf) {
#pragma unroll
      for (int rt = 0; rt < 4; ++rt)
#pragma unroll
        for (int r = 0; r < 4; ++r) {
          float v = acc[rt][cf][r] + a2r[cf];
          px[rt][r] += fmaxf(v, 0.f) * wfr[cf];
        }
    }
#pragma unroll
    for (int rt = 0; rt < 4; ++rt)
#pragma unroll
      for (int r = 0; r < 4; ++r) {
        float p_ = px[rt][r];
        p_ += __shfl_xor(p_, 1);
        p_ += __shfl_xor(p_, 2);
        p_ += __shfl_xor(p_, 4);
        p_ += __shfl_xor(p_, 8);
        px[rt][r] = p_;
      }
    if (l15 == 0) {
#pragma unroll
      for (int rt = 0; rt < 4; ++rt)
#pragma unroll
        for (int r = 0; r < 4; ++r)
          red[wave * 64 + rt * 16 + lq * 4 + r] = px[rt][r];
    }
    __syncthreads();   // B1
    float sc = 0.f;
#pragma unroll
    for (int w8 = 0; w8 < 8; ++w8) sc += red[w8 * 64 + lane];
    if (t < 64) attg[tg * 64 + t] = sc;
    float m = sc;
#pragma unroll
    for (int off = 1; off < 64; off <<= 1) m = fmaxf(m, __shfl_xor(m, off));
    float p = expf(sc - m);
    float Z = p;
#pragma unroll
    for (int off = 1; off < 64; off <<= 1) Z += __shfl_xor(Z, off);
    if (t < 64) pl[t] = p;
    __syncthreads();   // B2

    {
      int half = t >> 8;
      int e = (t & 255) * 2;
      float o0 = 0.f, o1 = 0.f;
#pragma unroll
      for (int i = 0; i < 32; ++i) {
        int row = half * 32 + i;
        float pw = pl[row];
        int byt = (row * 1024 + e * 2) ^ ((row & 7) << 4);
        unsigned u = *reinterpret_cast<const unsigned*>(smem + byt);
        o0 += pw * __uint_as_float(u << 16);
        o1 += pw * __uint_as_float(u & 0xffff0000u);
      }
      __syncthreads();   // all PV A-reads done (also xch-WAR safety)
      float2* xch = (float2*)red;
      if (half) xch[t - 256] = make_float2(o0, o1);
      __syncthreads();   // B3: xch ready; q0/q1 LDS slots now dead
      if (!half) {
        float2 hv = xch[t];
        *reinterpret_cast<float2*>(ogp + tg * 512 + e) =
            make_float2(o0 + hv.x, o1 + hv.y);
      }
      if (t == 0) {
        mzg[tg * 2] = m;
        mzg[tg * 2 + 1] = Z;
      }
    }

    if (T < 3) {
      // write next tile's q0,q1 (loads issued before the epilogue)
      G_WRITE(0, 0, h0, h1)
      G_WRITE(0, 1, h2, h3)
      G_WRITE(1, 0, h4, h5)
      G_WRITE(1, 1, h6, h7)
      __syncthreads();   // B4: staged before next tile's ki0
    }
  }
#undef K_STEP
#undef G_LOAD
#undef G_LOADN
#undef G_WRITE
}

// ---------------------------------------------------------------------------
// Kernel 3: merge 16 per-tile (m,Z,o) partials per batch; emit weighted+alpha.
__global__ void k_final(const float* __restrict__ attg,
                        const float* __restrict__ ogp,
                        const float* __restrict__ mzg,
                        float* __restrict__ weighted,
                        float* __restrict__ alpha) {
  int b = blockIdx.x;   // 0..127
  int t = threadIdx.x;  // 512
  float mv[16], zv[16];
  float m = -__builtin_huge_valf();
#pragma unroll
  for (int i = 0; i < 16; ++i) {
    mv[i] = mzg[(b * 16 + i) * 2];
    zv[i] = mzg[(b * 16 + i) * 2 + 1];
    m = fmaxf(m, mv[i]);
  }
  float Z = 0.f;
#pragma unroll
  for (int i = 0; i < 16; ++i) {
    float s = expf(mv[i] - m);
    mv[i] = s;
    Z += s * zv[i];
  }
  float inv = 1.f / Z;
  float o = 0.f;
#pragma unroll
  for (int i = 0; i < 16; ++i) o += mv[i] * ogp[((long)b * 16 + i) * 512 + t];
  weighted[b * NE + t] = o * inv;
  alpha[b * NL + t] = expf(attg[b * NL + t] - m) * inv;
  alpha[b * NL + 512 + t] = expf(attg[b * NL + 512 + t] - m) * inv;
}

// ---------------------------------------------------------------------------
extern "C" void kernel_launch(void* const* d_in, const int* in_sizes, int n_in,
                              void* d_out, int out_size, void* d_ws, size_t ws_size,
                              hipStream_t stream) {
  const float* enc    = (const float*)d_in[0];  // [B,L,E]
  const float* dec    = (const float*)d_in[1];  // [B,D]
  const float* W_enc  = (const float*)d_in[2];  // [E,A]
  const float* b_enc  = (const float*)d_in[3];  // [A]
  const float* W_dec  = (const float*)d_in[4];  // [D,A]
  const float* b_dec  = (const float*)d_in[5];  // [A]
  const float* W_full = (const float*)d_in[6];  // [A]
  // d_in[7] = b_full: cancels in softmax, unused.

  float* out = (float*)d_out;
  float* weighted = out;                 // [B,E]
  float* alpha = out + NB * NE;          // [B,L]

  char* ws = (char*)d_ws;
  float* att2          = (float*)ws;                           // 256 KB
  unsigned short* Bpk  = (unsigned short*)(ws + (256 << 10));  // 512 KB
  float* attg          = (float*)(ws + (768 << 10));           // 512 KB
  float* ogp           = (float*)(ws + (1280 << 10));          // 4 MB
  float* mzg           = (float*)(ws + (5376 << 10));          // 16 KB

  hipLaunchKernelGGL(k_prep, dim3(192), dim3(512), 0, stream,
                     W_enc, Bpk, dec, W_dec, b_enc, b_dec, att2);
  hipLaunchKernelGGL(k_main, dim3(512), dim3(512), 67840, stream,
                     enc, Bpk, att2, W_full, attg, ogp, mzg);
  hipLaunchKernelGGL(k_final, dim3(NB), dim3(512), 0, stream,
                     attg, ogp, mzg, weighted, alpha);
}

// Round 17
// 135.842 us; speedup vs baseline: 4.6136x; 4.6136x over previous
//
#include <hip/hip_runtime.h>

// Problem constants
#define NB 128
#define NL 1024
#define NE 512
#define NA 512
#define ND 512

typedef __attribute__((ext_vector_type(8))) short short8;
typedef __attribute__((ext_vector_type(4))) float f32x4;

static __device__ __forceinline__ unsigned short f2bf(float f) {
  unsigned int u = __float_as_uint(f);
  u += 0x7FFF + ((u >> 16) & 1);   // round-to-nearest-even
  return (unsigned short)(u >> 16);
}

// ---------------------------------------------------------------------------
// Kernel 1 (160 blocks x 1024 thr): blocks 0..31 pack W_enc -> bf16 MFMA
// B-fragment order, CONTIGUOUS-PER-WAVE: short8 index
//   ((ki*8 + w)*64 + lane)*4 + cf   (w = nf>>2, cf = nf&3)
// so a k_main wave's 4 fragments sit at consecutive 64B per lane.
// Blocks 32..159: att2[b][a] = dec[b]@W_dec[:,a] + b_dec[a] + b_enc[a],
// d-split 2-way across the 1024 threads (halves the serial FMA chain).
__global__ void k_prep(const float* __restrict__ W_enc,
                       unsigned short* __restrict__ Bpack,
                       const float* __restrict__ dec,
                       const float* __restrict__ Wdec,
                       const float* __restrict__ b_enc,
                       const float* __restrict__ b_dec,
                       float* __restrict__ att2) {
  __shared__ float part[512];
  int blk = blockIdx.x;
  int tid = threadIdx.x;  // 1024
  if (blk < 32) {
    int t = blk * 1024 + tid;   // 0..32767
    int lane = t & 63;
    int rest = t >> 6;
    int nf = rest & 31;
    int ki = rest >> 5;
    int col = nf * 16 + (lane & 15);
    int kbase = ki * 32 + (lane >> 4) * 8;
    short8 v;
#pragma unroll
    for (int j = 0; j < 8; ++j)
      v[j] = (short)f2bf(W_enc[(kbase + j) * NA + col]);
    long dst = ((long)(ki * 8 + (nf >> 2)) * 64 + lane) * 4 + (nf & 3);
    *reinterpret_cast<short8*>(Bpack + dst * 8) = v;
  } else {
    int b = blk - 32;
    int a = tid & 511;
    int dh = tid >> 9;          // 0 or 1
    float acc = dh ? 0.f : (b_enc[a] + b_dec[a]);
    const float* drow = dec + b * ND + dh * 256;
    const float* wcol = Wdec + (dh * 256) * NA + a;
#pragma unroll 8
    for (int d = 0; d < 256; ++d)
      acc += drow[d] * wcol[d * NA];
    if (dh) part[a] = acc;
    __syncthreads();
    if (!dh) att2[b * NA + a] = acc + part[a];
  }
}

// ---------------------------------------------------------------------------
// Kernel 2: fused scores + per-block softmax-partial + PV (exact R10
// structure, 123.7us baseline). 2048 blocks x 64 rows, 512 thr (8 waves),
// 2 blocks/CU. K-interleaved A staging: prologue stages q0,q1; q2,q3 loaded
// during ki0-5, written ki2-7, one barrier before ki8. A: LDS bf16 [64][512]
// XOR-swizzled. B: per-ki L2->reg, NOW from contiguous-per-wave Bpack (one
// base + 3 imm offsets per step). One redundant PV barrier removed.
__global__ __attribute__((amdgpu_waves_per_eu(4))) __launch_bounds__(512)
void k_main(const float* __restrict__ enc,
            const unsigned short* __restrict__ Bpack,
            const float* __restrict__ att2g, const float* __restrict__ wfull,
            float* __restrict__ attg, float* __restrict__ ogp,
            float* __restrict__ mzg) {
  extern __shared__ char smem[];       // 64KB A | 2KB red | 256B p
  const int t = threadIdx.x;
  const int lane = t & 63;
  const int wave = t >> 6;
  const int l15 = lane & 15;
  const int lq = lane >> 4;
  const int blk = blockIdx.x;          // 0..2047
  const int batch = blk >> 4;          // 16 blocks per batch
  const long row0 = (long)blk * 64;
  const int srow16 = t >> 4;           // 0..31 (staging row within half)
  const int scol8 = t & 15;            // staging col8

  // Staging chunk (Q, FI): row = FI*32 + srow16, k0 = Q*128 + scol8*8.
#define G_LOAD(Q, FI, GA, GB)                                                 \
  {                                                                           \
    int row = (FI)*32 + srow16;                                               \
    const float* src = enc + (row0 + row) * NE + (Q)*128 + scol8 * 8;         \
    GA = *reinterpret_cast<const float4*>(src);                               \
    GB = *reinterpret_cast<const float4*>(src + 4);                           \
  }
#define G_WRITE(Q, FI, GA, GB)                                                \
  {                                                                           \
    int row = (FI)*32 + srow16;                                               \
    short8 o;                                                                 \
    o[0] = (short)f2bf(GA.x); o[1] = (short)f2bf(GA.y);                       \
    o[2] = (short)f2bf(GA.z); o[3] = (short)f2bf(GA.w);                       \
    o[4] = (short)f2bf(GB.x); o[5] = (short)f2bf(GB.y);                       \
    o[6] = (short)f2bf(GB.z); o[7] = (short)f2bf(GB.w);                       \
    int byt = (row * 1024 + (Q)*256 + scol8 * 16) ^ ((row & 7) << 4);         \
    *reinterpret_cast<short8*>(smem + byt) = o;                               \
  }

  // ---- prologue: stage quarters 0,1 (k 0..255) ----
  {
    float4 h[8];
#pragma unroll
    for (int c = 0; c < 4; ++c) {
      int q = c >> 1;
      int row = (c & 1) * 32 + srow16;
      const float* src = enc + (row0 + row) * NE + q * 128 + scol8 * 8;
      h[c * 2] = *reinterpret_cast<const float4*>(src);
      h[c * 2 + 1] = *reinterpret_cast<const float4*>(src + 4);
    }
#pragma unroll
    for (int c = 0; c < 4; ++c) {
      int q = c >> 1;
      int row = (c & 1) * 32 + srow16;
      float4 xa = h[c * 2], xb = h[c * 2 + 1];
      short8 o;
      o[0] = (short)f2bf(xa.x); o[1] = (short)f2bf(xa.y);
      o[2] = (short)f2bf(xa.z); o[3] = (short)f2bf(xa.w);
      o[4] = (short)f2bf(xb.x); o[5] = (short)f2bf(xb.y);
      o[6] = (short)f2bf(xb.z); o[7] = (short)f2bf(xb.w);
      int byt = (row * 1024 + q * 256 + scol8 * 16) ^ ((row & 7) << 4);
      *reinterpret_cast<short8*>(smem + byt) = o;
    }
  }
  __syncthreads();

  f32x4 acc[4][4];
#pragma unroll
  for (int rt = 0; rt < 4; ++rt)
#pragma unroll
    for (int cf = 0; cf < 4; ++cf) acc[rt][cf] = (f32x4){0.f, 0.f, 0.f, 0.f};

  const short8* bp = reinterpret_cast<const short8*>(Bpack);
#define K_STEP(KI)                                                            \
  {                                                                           \
    const short8* bb = bp + ((long)((KI)*8 + wave) * 64 + lane) * 4;          \
    short8 bv0 = bb[0];                                                       \
    short8 bv1 = bb[1];                                                       \
    short8 bv2 = bb[2];                                                       \
    short8 bv3 = bb[3];                                                       \
    _Pragma("unroll") for (int rt = 0; rt < 4; ++rt) {                        \
      int row = rt * 16 + l15;                                                \
      int byt = (row * 1024 + (KI)*64 + lq * 16) ^ ((row & 7) << 4);          \
      short8 av = *reinterpret_cast<const short8*>(smem + byt);               \
      acc[rt][0] = __builtin_amdgcn_mfma_f32_16x16x32_bf16(av, bv0, acc[rt][0], 0, 0, 0); \
      acc[rt][1] = __builtin_amdgcn_mfma_f32_16x16x32_bf16(av, bv1, acc[rt][1], 0, 0, 0); \
      acc[rt][2] = __builtin_amdgcn_mfma_f32_16x16x32_bf16(av, bv2, acc[rt][2], 0, 0, 0); \
      acc[rt][3] = __builtin_amdgcn_mfma_f32_16x16x32_bf16(av, bv3, acc[rt][3], 0, 0, 0); \
    }                                                                         \
  }

  {
    float4 g0, g1, g2, g3;
    G_LOAD(2, 0, g0, g1) K_STEP(0)
    G_LOAD(2, 1, g2, g3) K_STEP(1)
    G_WRITE(2, 0, g0, g1) K_STEP(2)
    G_WRITE(2, 1, g2, g3) K_STEP(3)
    G_LOAD(3, 0, g0, g1) K_STEP(4)
    G_LOAD(3, 1, g2, g3) K_STEP(5)
    G_WRITE(3, 0, g0, g1) K_STEP(6)
    G_WRITE(3, 1, g2, g3) K_STEP(7)
  }
  __syncthreads();   // quarters 2,3 staged by all waves before ki8 reads
  K_STEP(8)  K_STEP(9)  K_STEP(10) K_STEP(11)
  K_STEP(12) K_STEP(13) K_STEP(14) K_STEP(15)
#undef K_STEP
#undef G_LOAD
#undef G_WRITE

  // ---- epilogue: scores -> m,Z,p -> PV partial ----
  float a2r[4], wfr[4];
#pragma unroll
  for (int cf = 0; cf < 4; ++cf) {
    int col = wave * 64 + cf * 16 + l15;
    a2r[cf] = att2g[batch * NA + col];
    wfr[cf] = wfull[col];
  }
  float px[4][4];
#pragma unroll
  for (int rt = 0; rt < 4; ++rt)
#pragma unroll
    for (int r = 0; r < 4; ++r) px[rt][r] = 0.f;
#pragma unroll
  for (int cf = 0; cf < 4; ++cf) {
#pragma unroll
    for (int rt = 0; rt < 4; ++rt)
#pragma unroll
      for (int r = 0; r < 4; ++r) {
        float v = acc[rt][cf][r] + a2r[cf];
        px[rt][r] += fmaxf(v, 0.f) * wfr[cf];
      }
  }
#pragma unroll
  for (int rt = 0; rt < 4; ++rt)
#pragma unroll
    for (int r = 0; r < 4; ++r) {
      float p_ = px[rt][r];
      p_ += __shfl_xor(p_, 1);
      p_ += __shfl_xor(p_, 2);
      p_ += __shfl_xor(p_, 4);
      p_ += __shfl_xor(p_, 8);
      px[rt][r] = p_;
    }
  float* red = (float*)(smem + 65536);        // 512 f
  float* pl = (float*)(smem + 65536 + 2048);  // 64 f
  if (l15 == 0) {
#pragma unroll
    for (int rt = 0; rt < 4; ++rt)
#pragma unroll
      for (int r = 0; r < 4; ++r)
        red[wave * 64 + rt * 16 + lq * 4 + r] = px[rt][r];
  }
  __syncthreads();
  float sc = 0.f;
#pragma unroll
  for (int w8 = 0; w8 < 8; ++w8) sc += red[w8 * 64 + lane];
  if (t < 64) attg[blk * 64 + t] = sc;
  float m = sc;
#pragma unroll
  for (int off = 1; off < 64; off <<= 1) m = fmaxf(m, __shfl_xor(m, off));
  float p = expf(sc - m);
  float Z = p;
#pragma unroll
  for (int off = 1; off < 64; off <<= 1) Z += __shfl_xor(Z, off);
  if (t < 64) pl[t] = p;
  __syncthreads();   // B2: pl visible; red dead (sc reads complete)

  {
    int half = t >> 8;
    int e = (t & 255) * 2;
    float o0 = 0.f, o1 = 0.f;
#pragma unroll
    for (int i = 0; i < 32; ++i) {
      int row = half * 32 + i;
      float pw = pl[row];
      int byt = (row * 1024 + e * 2) ^ ((row & 7) << 4);
      unsigned u = *reinterpret_cast<const unsigned*>(smem + byt);
      o0 += pw * __uint_as_float(u << 16);
      o1 += pw * __uint_as_float(u & 0xffff0000u);
    }
    // (pre-xch barrier removed: B2 already ordered the last red reads;
    // xch writes touch only the red region, disjoint from A and pl.)
    float2* xch = (float2*)red;
    if (half) xch[t - 256] = make_float2(o0, o1);
    __syncthreads();
    if (!half) {
      float2 hv = xch[t];
      *reinterpret_cast<float2*>(ogp + (long)blk * 512 + e) =
          make_float2(o0 + hv.x, o1 + hv.y);
    }
    if (t == 0) {
      mzg[blk * 2] = m;
      mzg[blk * 2 + 1] = Z;
    }
  }
}

// ---------------------------------------------------------------------------
// Kernel 3: merge 16 per-block (m,Z,o) partials per batch; emit weighted+alpha.
__global__ void k_final(const float* __restrict__ attg,
                        const float* __restrict__ ogp,
                        const float* __restrict__ mzg,
                        float* __restrict__ weighted,
                        float* __restrict__ alpha) {
  int b = blockIdx.x;   // 0..127
  int t = threadIdx.x;  // 512
  float mv[16], zv[16];
  float m = -__builtin_huge_valf();
#pragma unroll
  for (int i = 0; i < 16; ++i) {
    mv[i] = mzg[(b * 16 + i) * 2];
    zv[i] = mzg[(b * 16 + i) * 2 + 1];
    m = fmaxf(m, mv[i]);
  }
  float Z = 0.f;
#pragma unroll
  for (int i = 0; i < 16; ++i) {
    float s = expf(mv[i] - m);
    mv[i] = s;
    Z += s * zv[i];
  }
  float inv = 1.f / Z;
  float o = 0.f;
#pragma unroll
  for (int i = 0; i < 16; ++i) o += mv[i] * ogp[((long)b * 16 + i) * 512 + t];
  weighted[b * NE + t] = o * inv;
  alpha[b * NL + t] = expf(attg[b * NL + t] - m) * inv;
  alpha[b * NL + 512 + t] = expf(attg[b * NL + 512 + t] - m) * inv;
}

// ---------------------------------------------------------------------------
extern "C" void kernel_launch(void* const* d_in, const int* in_sizes, int n_in,
                              void* d_out, int out_size, void* d_ws, size_t ws_size,
                              hipStream_t stream) {
  const float* enc    = (const float*)d_in[0];  // [B,L,E]
  const float* dec    = (const float*)d_in[1];  // [B,D]
  const float* W_enc  = (const float*)d_in[2];  // [E,A]
  const float* b_enc  = (const float*)d_in[3];  // [A]
  const float* W_dec  = (const float*)d_in[4];  // [D,A]
  const float* b_dec  = (const float*)d_in[5];  // [A]
  const float* W_full = (const float*)d_in[6];  // [A]
  // d_in[7] = b_full: cancels in softmax, unused.

  float* out = (float*)d_out;
  float* weighted = out;                 // [B,E]
  float* alpha = out + NB * NE;          // [B,L]

  char* ws = (char*)d_ws;
  float* att2          = (float*)ws;                           // 256 KB
  unsigned short* Bpk  = (unsigned short*)(ws + (256 << 10));  // 512 KB
  float* attg          = (float*)(ws + (768 << 10));           // 512 KB
  float* ogp           = (float*)(ws + (1280 << 10));          // 4 MB
  float* mzg           = (float*)(ws + (5376 << 10));          // 16 KB

  hipLaunchKernelGGL(k_prep, dim3(160), dim3(1024), 0, stream,
                     W_enc, Bpk, dec, W_dec, b_enc, b_dec, att2);
  hipLaunchKernelGGL(k_main, dim3(2048), dim3(512), 67840, stream,
                     enc, Bpk, att2, W_full, attg, ogp, mzg);
  hipLaunchKernelGGL(k_final, dim3(NB), dim3(512), 0, stream,
                     attg, ogp, mzg, weighted, alpha);
}

// Round 18
// 115.295 us; speedup vs baseline: 5.4357x; 1.1782x over previous
//
#include <hip/hip_runtime.h>

// Problem constants
#define NB 128
#define NL 1024
#define NE 512
#define NA 512
#define ND 512

typedef __attribute__((ext_vector_type(8))) short short8;
typedef __attribute__((ext_vector_type(4))) float f32x4;

static __device__ __forceinline__ unsigned short f2bf(float f) {
  unsigned int u = __float_as_uint(f);
  u += 0x7FFF + ((u >> 16) & 1);   // round-to-nearest-even
  return (unsigned short)(u >> 16);
}

// ---------------------------------------------------------------------------
// Kernel 1 (160 blocks x 1024 thr): blocks 0..31 pack W_enc -> bf16 MFMA
// B-fragment order, R10's COALESCED layout: [ki=0..15][nf=0..31][lane][j]
// (a wave's per-instruction load = contiguous 1KB; R17's per-wave-contiguous
// variant made each load a 64B-strided gather -> 4x L2 requests, reverted).
// Blocks 32..159: att2[b][a] = dec[b]@W_dec[:,a] + b_dec[a] + b_enc[a],
// d-split 2-way across 1024 threads (halves the serial FMA chain).
__global__ void k_prep(const float* __restrict__ W_enc,
                       unsigned short* __restrict__ Bpack,
                       const float* __restrict__ dec,
                       const float* __restrict__ Wdec,
                       const float* __restrict__ b_enc,
                       const float* __restrict__ b_dec,
                       float* __restrict__ att2) {
  __shared__ float part[512];
  int blk = blockIdx.x;
  int tid = threadIdx.x;  // 1024
  if (blk < 32) {
    int t = blk * 1024 + tid;   // 0..32767
    int lane = t & 63;
    int rest = t >> 6;          // rest = ki*32 + nf
    int nf = rest & 31;
    int ki = rest >> 5;
    int col = nf * 16 + (lane & 15);
    int kbase = ki * 32 + (lane >> 4) * 8;
    short8 v;
#pragma unroll
    for (int j = 0; j < 8; ++j)
      v[j] = (short)f2bf(W_enc[(kbase + j) * NA + col]);
    *reinterpret_cast<short8*>(Bpack + (long)t * 8) = v;
  } else {
    int b = blk - 32;
    int a = tid & 511;
    int dh = tid >> 9;          // 0 or 1
    float acc = dh ? 0.f : (b_enc[a] + b_dec[a]);
    const float* drow = dec + b * ND + dh * 256;
    const float* wcol = Wdec + (dh * 256) * NA + a;
#pragma unroll 8
    for (int d = 0; d < 256; ++d)
      acc += drow[d] * wcol[d * NA];
    if (dh) part[a] = acc;
    __syncthreads();
    if (!dh) att2[b * NA + a] = acc + part[a];
  }
}

// ---------------------------------------------------------------------------
// Kernel 2: fused scores + per-block softmax-partial + PV — exact R10
// structure (123.7us proven best). 2048 blocks x 64 rows, 512 thr (8 waves),
// 2 blocks/CU. K-interleaved A staging: prologue stages q0,q1; q2,q3 loaded
// during ki0-5, written ki2-7, one barrier before ki8. A: LDS bf16 [64][512]
// XOR-swizzled. B: per-ki L2->reg from the coalesced Bpack. Redundant PV
// barrier removed (verified R17).
__global__ __attribute__((amdgpu_waves_per_eu(4))) __launch_bounds__(512)
void k_main(const float* __restrict__ enc,
            const unsigned short* __restrict__ Bpack,
            const float* __restrict__ att2g, const float* __restrict__ wfull,
            float* __restrict__ attg, float* __restrict__ ogp,
            float* __restrict__ mzg) {
  extern __shared__ char smem[];       // 64KB A | 2KB red | 256B p
  const int t = threadIdx.x;
  const int lane = t & 63;
  const int wave = t >> 6;
  const int l15 = lane & 15;
  const int lq = lane >> 4;
  const int blk = blockIdx.x;          // 0..2047
  const int batch = blk >> 4;          // 16 blocks per batch
  const long row0 = (long)blk * 64;
  const int srow16 = t >> 4;           // 0..31 (staging row within half)
  const int scol8 = t & 15;            // staging col8

  // Staging chunk (Q, FI): row = FI*32 + srow16, k0 = Q*128 + scol8*8.
#define G_LOAD(Q, FI, GA, GB)                                                 \
  {                                                                           \
    int row = (FI)*32 + srow16;                                               \
    const float* src = enc + (row0 + row) * NE + (Q)*128 + scol8 * 8;         \
    GA = *reinterpret_cast<const float4*>(src);                               \
    GB = *reinterpret_cast<const float4*>(src + 4);                           \
  }
#define G_WRITE(Q, FI, GA, GB)                                                \
  {                                                                           \
    int row = (FI)*32 + srow16;                                               \
    short8 o;                                                                 \
    o[0] = (short)f2bf(GA.x); o[1] = (short)f2bf(GA.y);                       \
    o[2] = (short)f2bf(GA.z); o[3] = (short)f2bf(GA.w);                       \
    o[4] = (short)f2bf(GB.x); o[5] = (short)f2bf(GB.y);                       \
    o[6] = (short)f2bf(GB.z); o[7] = (short)f2bf(GB.w);                       \
    int byt = (row * 1024 + (Q)*256 + scol8 * 16) ^ ((row & 7) << 4);         \
    *reinterpret_cast<short8*>(smem + byt) = o;                               \
  }

  // ---- prologue: stage quarters 0,1 (k 0..255) ----
  {
    float4 h[8];
#pragma unroll
    for (int c = 0; c < 4; ++c) {
      int q = c >> 1;
      int row = (c & 1) * 32 + srow16;
      const float* src = enc + (row0 + row) * NE + q * 128 + scol8 * 8;
      h[c * 2] = *reinterpret_cast<const float4*>(src);
      h[c * 2 + 1] = *reinterpret_cast<const float4*>(src + 4);
    }
#pragma unroll
    for (int c = 0; c < 4; ++c) {
      int q = c >> 1;
      int row = (c & 1) * 32 + srow16;
      float4 xa = h[c * 2], xb = h[c * 2 + 1];
      short8 o;
      o[0] = (short)f2bf(xa.x); o[1] = (short)f2bf(xa.y);
      o[2] = (short)f2bf(xa.z); o[3] = (short)f2bf(xa.w);
      o[4] = (short)f2bf(xb.x); o[5] = (short)f2bf(xb.y);
      o[6] = (short)f2bf(xb.z); o[7] = (short)f2bf(xb.w);
      int byt = (row * 1024 + q * 256 + scol8 * 16) ^ ((row & 7) << 4);
      *reinterpret_cast<short8*>(smem + byt) = o;
    }
  }
  __syncthreads();

  f32x4 acc[4][4];
#pragma unroll
  for (int rt = 0; rt < 4; ++rt)
#pragma unroll
    for (int cf = 0; cf < 4; ++cf) acc[rt][cf] = (f32x4){0.f, 0.f, 0.f, 0.f};

  const short8* bp = reinterpret_cast<const short8*>(Bpack);
#define K_STEP(KI)                                                            \
  {                                                                           \
    short8 bv0 = bp[((KI)*32 + wave * 4 + 0) * 64 + lane];                    \
    short8 bv1 = bp[((KI)*32 + wave * 4 + 1) * 64 + lane];                    \
    short8 bv2 = bp[((KI)*32 + wave * 4 + 2) * 64 + lane];                    \
    short8 bv3 = bp[((KI)*32 + wave * 4 + 3) * 64 + lane];                    \
    _Pragma("unroll") for (int rt = 0; rt < 4; ++rt) {                        \
      int row = rt * 16 + l15;                                                \
      int byt = (row * 1024 + (KI)*64 + lq * 16) ^ ((row & 7) << 4);          \
      short8 av = *reinterpret_cast<const short8*>(smem + byt);               \
      acc[rt][0] = __builtin_amdgcn_mfma_f32_16x16x32_bf16(av, bv0, acc[rt][0], 0, 0, 0); \
      acc[rt][1] = __builtin_amdgcn_mfma_f32_16x16x32_bf16(av, bv1, acc[rt][1], 0, 0, 0); \
      acc[rt][2] = __builtin_amdgcn_mfma_f32_16x16x32_bf16(av, bv2, acc[rt][2], 0, 0, 0); \
      acc[rt][3] = __builtin_amdgcn_mfma_f32_16x16x32_bf16(av, bv3, acc[rt][3], 0, 0, 0); \
    }                                                                         \
  }

  {
    float4 g0, g1, g2, g3;
    G_LOAD(2, 0, g0, g1) K_STEP(0)
    G_LOAD(2, 1, g2, g3) K_STEP(1)
    G_WRITE(2, 0, g0, g1) K_STEP(2)
    G_WRITE(2, 1, g2, g3) K_STEP(3)
    G_LOAD(3, 0, g0, g1) K_STEP(4)
    G_LOAD(3, 1, g2, g3) K_STEP(5)
    G_WRITE(3, 0, g0, g1) K_STEP(6)
    G_WRITE(3, 1, g2, g3) K_STEP(7)
  }
  __syncthreads();   // quarters 2,3 staged by all waves before ki8 reads
  K_STEP(8)  K_STEP(9)  K_STEP(10) K_STEP(11)
  K_STEP(12) K_STEP(13) K_STEP(14) K_STEP(15)
#undef K_STEP
#undef G_LOAD
#undef G_WRITE

  // ---- epilogue: scores -> m,Z,p -> PV partial ----
  float a2r[4], wfr[4];
#pragma unroll
  for (int cf = 0; cf < 4; ++cf) {
    int col = wave * 64 + cf * 16 + l15;
    a2r[cf] = att2g[batch * NA + col];
    wfr[cf] = wfull[col];
  }
  float px[4][4];
#pragma unroll
  for (int rt = 0; rt < 4; ++rt)
#pragma unroll
    for (int r = 0; r < 4; ++r) px[rt][r] = 0.f;
#pragma unroll
  for (int cf = 0; cf < 4; ++cf) {
#pragma unroll
    for (int rt = 0; rt < 4; ++rt)
#pragma unroll
      for (int r = 0; r < 4; ++r) {
        float v = acc[rt][cf][r] + a2r[cf];
        px[rt][r] += fmaxf(v, 0.f) * wfr[cf];
      }
  }
#pragma unroll
  for (int rt = 0; rt < 4; ++rt)
#pragma unroll
    for (int r = 0; r < 4; ++r) {
      float p_ = px[rt][r];
      p_ += __shfl_xor(p_, 1);
      p_ += __shfl_xor(p_, 2);
      p_ += __shfl_xor(p_, 4);
      p_ += __shfl_xor(p_, 8);
      px[rt][r] = p_;
    }
  float* red = (float*)(smem + 65536);        // 512 f
  float* pl = (float*)(smem + 65536 + 2048);  // 64 f
  if (l15 == 0) {
#pragma unroll
    for (int rt = 0; rt < 4; ++rt)
#pragma unroll
      for (int r = 0; r < 4; ++r)
        red[wave * 64 + rt * 16 + lq * 4 + r] = px[rt][r];
  }
  __syncthreads();
  float sc = 0.f;
#pragma unroll
  for (int w8 = 0; w8 < 8; ++w8) sc += red[w8 * 64 + lane];
  if (t < 64) attg[blk * 64 + t] = sc;
  float m = sc;
#pragma unroll
  for (int off = 1; off < 64; off <<= 1) m = fmaxf(m, __shfl_xor(m, off));
  float p = expf(sc - m);
  float Z = p;
#pragma unroll
  for (int off = 1; off < 64; off <<= 1) Z += __shfl_xor(Z, off);
  if (t < 64) pl[t] = p;
  __syncthreads();   // B2: pl visible; red reads (sc) complete

  {
    int half = t >> 8;
    int e = (t & 255) * 2;
    float o0 = 0.f, o1 = 0.f;
#pragma unroll
    for (int i = 0; i < 32; ++i) {
      int row = half * 32 + i;
      float pw = pl[row];
      int byt = (row * 1024 + e * 2) ^ ((row & 7) << 4);
      unsigned u = *reinterpret_cast<const unsigned*>(smem + byt);
      o0 += pw * __uint_as_float(u << 16);
      o1 += pw * __uint_as_float(u & 0xffff0000u);
    }
    float2* xch = (float2*)red;
    if (half) xch[t - 256] = make_float2(o0, o1);
    __syncthreads();
    if (!half) {
      float2 hv = xch[t];
      *reinterpret_cast<float2*>(ogp + (long)blk * 512 + e) =
          make_float2(o0 + hv.x, o1 + hv.y);
    }
    if (t == 0) {
      mzg[blk * 2] = m;
      mzg[blk * 2 + 1] = Z;
    }
  }
}

// ---------------------------------------------------------------------------
// Kernel 3: merge 16 per-block (m,Z,o) partials per batch; emit weighted+alpha.
__global__ void k_final(const float* __restrict__ attg,
                        const float* __restrict__ ogp,
                        const float* __restrict__ mzg,
                        float* __restrict__ weighted,
                        float* __restrict__ alpha) {
  int b = blockIdx.x;   // 0..127
  int t = threadIdx.x;  // 512
  float mv[16], zv[16];
  float m = -__builtin_huge_valf();
#pragma unroll
  for (int i = 0; i < 16; ++i) {
    mv[i] = mzg[(b * 16 + i) * 2];
    zv[i] = mzg[(b * 16 + i) * 2 + 1];
    m = fmaxf(m, mv[i]);
  }
  float Z = 0.f;
#pragma unroll
  for (int i = 0; i < 16; ++i) {
    float s = expf(mv[i] - m);
    mv[i] = s;
    Z += s * zv[i];
  }
  float inv = 1.f / Z;
  float o = 0.f;
#pragma unroll
  for (int i = 0; i < 16; ++i) o += mv[i] * ogp[((long)b * 16 + i) * 512 + t];
  weighted[b * NE + t] = o * inv;
  alpha[b * NL + t] = expf(attg[b * NL + t] - m) * inv;
  alpha[b * NL + 512 + t] = expf(attg[b * NL + 512 + t] - m) * inv;
}

// ---------------------------------------------------------------------------
extern "C" void kernel_launch(void* const* d_in, const int* in_sizes, int n_in,
                              void* d_out, int out_size, void* d_ws, size_t ws_size,
                              hipStream_t stream) {
  const float* enc    = (const float*)d_in[0];  // [B,L,E]
  const float* dec    = (const float*)d_in[1];  // [B,D]
  const float* W_enc  = (const float*)d_in[2];  // [E,A]
  const float* b_enc  = (const float*)d_in[3];  // [A]
  const float* W_dec  = (const float*)d_in[4];  // [D,A]
  const float* b_dec  = (const float*)d_in[5];  // [A]
  const float* W_full = (const float*)d_in[6];  // [A]
  // d_in[7] = b_full: cancels in softmax, unused.

  float* out = (float*)d_out;
  float* weighted = out;                 // [B,E]
  float* alpha = out + NB * NE;          // [B,L]

  char* ws = (char*)d_ws;
  float* att2          = (float*)ws;                           // 256 KB
  unsigned short* Bpk  = (unsigned short*)(ws + (256 << 10));  // 512 KB
  float* attg          = (float*)(ws + (768 << 10));           // 512 KB
  float* ogp           = (float*)(ws + (1280 << 10));          // 4 MB
  float* mzg           = (float*)(ws + (5376 << 10));          // 16 KB

  hipLaunchKernelGGL(k_prep, dim3(160), dim3(1024), 0, stream,
                     W_enc, Bpk, dec, W_dec, b_enc, b_dec, att2);
  hipLaunchKernelGGL(k_main, dim3(2048), dim3(512), 67840, stream,
                     enc, Bpk, att2, W_full, attg, ogp, mzg);
  hipLaunchKernelGGL(k_final, dim3(NB), dim3(512), 0, stream,
                     attg, ogp, mzg, weighted, alpha);
}